// Round 2
// baseline (130.119 us; speedup 1.0000x reference)
//
#include <hip/hip_runtime.h>
#include <hip/hip_bf16.h>

// (B,T,E,H) = (4, 2048, 1024, 64); scale = E^-0.5 = 1/32.
// Ground truth: inputs fp32, output fp32 (r7-r12 pass). ws >= 268 MB.
// dur_us model: ~87 us fixed harness ops (ws poison fill = 44 us x2 at ~6.1
// TB/s fill rate — immovable) + ~32 us controllable kernels/gaps.
// R13 (resubmit R14 — prior bench was a container-acquisition failure, kernel
// never ran): qkv -> 32-row/512-thr blocks (halves W L2 traffic 196->98 MB,
// halves LDS-write + barrier cost per output) + reg-staged prefetch to hide
// the vmcnt drain at 1 block/CU. attn -> balanced qt pairing (per-CU work
// constant), shfl-reduced lS epilogue (128->8 LDS reads), setprio on MFMA.
constexpr int Bc = 4;
constexpr int Tc = 2048;
constexpr int Ec = 1024;
constexpr int Hc = 64;
constexpr float SCALE = 0.03125f;

typedef short  short8  __attribute__((ext_vector_type(8)));
typedef float  floatx4 __attribute__((ext_vector_type(4)));

__device__ __forceinline__ unsigned short f2bf(float f) {  // RNE
    union { float f; unsigned int i; } x;
    x.f = f;
    unsigned int r = x.i + 0x7fffu + ((x.i >> 16) & 1u);
    return (unsigned short)(r >> 16);
}

// ---------------------------------------------------------------------------
// Kernel 0: W fp32 [E][H] -> Wt bf16 [H][E], x3 (r7-r12-proven). ~3 us.
// ---------------------------------------------------------------------------
__global__ __launch_bounds__(256) void prep_w(
    const float* __restrict__ Wq, const float* __restrict__ Wk,
    const float* __restrict__ Wv, unsigned short* __restrict__ Wt)
{
    const float* W = blockIdx.y == 0 ? Wq : (blockIdx.y == 1 ? Wk : Wv);
    unsigned short* D = Wt + (size_t)blockIdx.y * (Ec * Hc);
    const int i0 = blockIdx.x * 1024 + threadIdx.x * 4;
    const float4 f = *(const float4*)(W + i0);
    const float v[4] = {f.x, f.y, f.z, f.w};
    #pragma unroll
    for (int j = 0; j < 4; ++j) {
        const int i = i0 + j;            // i = e*64 + h
        D[(i & 63) * Ec + (i >> 6)] = f2bf(v[j]);
    }
}

// ---------------------------------------------------------------------------
// Kernel 1: FUSED QKV projection, MFMA 16x16x32 bf16, K=128 staging depth.
// R13 structure: grid 256 x 512 thr (1 block/CU, 8 waves = 2/SIMD, same 2048
// waves as before). Block = 32 X-rows, all three matrices -> W^T staged ONCE
// per 32 rows (was twice via 2x16-row blocks): W L2 traffic 196->98 MB, LDS
// writes per output halved, 16 barriers per 2x the work.
// Reg-staged prefetch (T14-lite): next tile's 2 float4 (X) + 6 uint4 (W)
// issued during MFMA phase; ds_write after barrier -> no exposed vmcnt drain
// even at 1 block/CU.
// Pad-136 rows: 2-way-free bank math (68%32==4, proven pad-72 class).
// Wave wv = (rowh = wv>>2, wq = wv&3); wave owns frags f=3*wq..3*wq+2 of its
// 16-row half (which=f>>2, ni=f&3) — r9/r12-proven fragment map.
// ---------------------------------------------------------------------------
__global__ __launch_bounds__(512, 2) void qkv_mfma9(
    const float* __restrict__ X, const unsigned short* __restrict__ Wt,
    unsigned short* __restrict__ Q, unsigned short* __restrict__ K,
    unsigned short* __restrict__ Vt)
{
    __shared__ __align__(16) unsigned short Xs[32][136];      //  8.5 KB
    __shared__ __align__(16) unsigned short Ws[3][64][136];   // 51.0 KB

    const int tid  = threadIdx.x;
    const int wv   = tid >> 6;          // 0..7
    const int lane = tid & 63;
    const int quad = lane >> 4;
    const int l16  = lane & 15;
    const int rowh = wv >> 2;           // 0..1 : 16-row half of the block
    const int wq   = wv & 3;            // frag-triple
    const size_t row0 = (size_t)blockIdx.x * 32;

    floatx4 acc[3];
    #pragma unroll
    for (int j = 0; j < 3; ++j)
        #pragma unroll
        for (int r = 0; r < 4; ++r) acc[j][r] = 0.f;

    const int xrow = tid >> 4;         // 0..31
    const int xc4  = (tid & 15) * 4;   // 0,4,..,60  (covers 64 cols per half)

    // ---- prologue loads (k0 = 0) into registers ----
    float4 xreg[2];
    uint4  wreg[6];
    #pragma unroll
    for (int h = 0; h < 2; ++h)
        xreg[h] = *(const float4*)(X + (row0 + xrow) * Ec + h * 64 + xc4);
    #pragma unroll
    for (int j = 0; j < 6; ++j) {
        const int flat = tid + 512 * j;         // 0..3071
        wreg[j] = *(const uint4*)(Wt + (flat >> 10) * 65536 +
                                  ((flat >> 4) & 63) * 1024 + (flat & 15) * 8);
    }

    for (int k0 = 0; k0 < Ec; k0 += 128) {
        __syncthreads();                 // previous MFMA phase done with LDS
        // ---- write staged registers to LDS ----
        #pragma unroll
        for (int h = 0; h < 2; ++h) {
            uint2 p;
            p.x = (unsigned int)f2bf(xreg[h].x) | ((unsigned int)f2bf(xreg[h].y) << 16);
            p.y = (unsigned int)f2bf(xreg[h].z) | ((unsigned int)f2bf(xreg[h].w) << 16);
            *(uint2*)&Xs[xrow][h * 64 + xc4] = p;
        }
        #pragma unroll
        for (int j = 0; j < 6; ++j) {
            const int flat = tid + 512 * j;
            *(uint4*)&Ws[flat >> 10][(flat >> 4) & 63][(flat & 15) * 8] = wreg[j];
        }
        // ---- issue next tile's loads (land under the MFMA phase) ----
        if (k0 + 128 < Ec) {
            #pragma unroll
            for (int h = 0; h < 2; ++h)
                xreg[h] = *(const float4*)(X + (row0 + xrow) * Ec + (k0 + 128) + h * 64 + xc4);
            #pragma unroll
            for (int j = 0; j < 6; ++j) {
                const int flat = tid + 512 * j;
                wreg[j] = *(const uint4*)(Wt + (flat >> 10) * 65536 +
                                          ((flat >> 4) & 63) * 1024 + (k0 + 128) + (flat & 15) * 8);
            }
        }
        __syncthreads();
        // ---- MFMA phase ----
        #pragma unroll
        for (int ks = 0; ks < 4; ++ks) {
            const short8 a = *(const short8*)&Xs[rowh * 16 + l16][ks * 32 + quad * 8];
            short8 b[3];
            #pragma unroll
            for (int j = 0; j < 3; ++j) {
                const int f = 3 * wq + j;
                b[j] = *(const short8*)&Ws[f >> 2][16 * (f & 3) + l16][ks * 32 + quad * 8];
            }
            #pragma unroll
            for (int j = 0; j < 3; ++j)
                acc[j] = __builtin_amdgcn_mfma_f32_16x16x32_bf16(a, b[j], acc[j], 0, 0, 0);
        }
    }

    // Epilogue. C/D: col = lane&15, row = quad*4 + reg (r7-r12-proven).
    const size_t rbase = row0 + rowh * 16;
    #pragma unroll
    for (int j = 0; j < 3; ++j) {
        const int f  = 3 * wq + j;
        const int mf = f >> 2, nf = f & 3;
        if (mf < 2) {
            unsigned short* O = mf == 0 ? Q : K;
            #pragma unroll
            for (int r = 0; r < 4; ++r) {
                float x = acc[j][r];
                if (!(x > -1.0e4f && x < 1.0e4f)) x = 11111.0f;   // diag
                O[(rbase + quad * 4 + r) * Hc + 16 * nf + l16] = f2bf(x);
            }
        } else {
            // V^T: Vt[b][h][t] (r8-proven). 16-row half shares one b.
            const size_t b  = rbase >> 11;
            const int    t0 = (int)(rbase & 2047) + quad * 4;
            unsigned short* VtB = Vt + b * ((size_t)Hc * Tc);
            unsigned int pk[2];
            #pragma unroll
            for (int half = 0; half < 2; ++half) {
                float x0 = acc[j][half * 2 + 0], x1 = acc[j][half * 2 + 1];
                if (!(x0 > -1.0e4f && x0 < 1.0e4f)) x0 = 11111.0f;
                if (!(x1 > -1.0e4f && x1 < 1.0e4f)) x1 = 11111.0f;
                pk[half] = (unsigned int)f2bf(x0) | ((unsigned int)f2bf(x1) << 16);
            }
            uint2 st; st.x = pk[0]; st.y = pk[1];
            *(uint2*)(VtB + (size_t)(16 * nf + l16) * Tc + t0) = st;
        }
    }
}

// ---------------------------------------------------------------------------
// Kernel 2: causal flash attention — r10/r11/r12-proven core, R13 polish:
//  * balanced dispatch: first 256 blocks qt=127..64 (desc), next 256 qt=0..63
//    (asc) -> CU c gets (qt, 64-..) pair summing to constant 129 k-tiles
//    (was: c and c+256 equally heavy -> 2x-mean tail).
//  * lS pre-reduced across l16 via 4x shfl_xor -> epilogue denom 8 LDS reads
//    (was 128 scalar), lS LDS 8 KB -> 0.5 KB.
//  * accS epilogue reads as float2.
//  * s_setprio(1) around MFMA clusters (barrier-free independent waves in
//    main loop — the m191-positive regime).
// ---------------------------------------------------------------------------
__global__ __launch_bounds__(512, 4) void attn_mfma6(
    const unsigned short* __restrict__ Q, const unsigned short* __restrict__ K,
    const unsigned short* __restrict__ Vt, float* __restrict__ Out)
{
    __shared__ __align__(16) unsigned short Pb[8][16][72];   // 18 KB
    __shared__ __align__(16) float accS[8][16][64];          // 32 KB
    __shared__ __align__(16) float lSr[8][16];               // 0.5 KB

    const int tid  = threadIdx.x;
    const int wv   = tid >> 6;            // 0..7
    const int lane = tid & 63;
    const int quad = lane >> 4;
    const int l16  = lane & 15;
    // balanced heavy/light pairing over dispatch-linear id
    const int id   = blockIdx.x + 128 * blockIdx.y;   // 0..511, dispatch order
    const int jj   = id & 255;
    const int qt   = (id < 256) ? (127 - (jj >> 2)) : (jj >> 2);
    const int b    = jj & 3;
    const int qend = qt * 16 + 16;
    const size_t base = (size_t)b * Tc * Hc;
    const unsigned short* VtB = Vt + (size_t)b * Hc * Tc;

    short8 aQ[2];
    #pragma unroll
    for (int ks = 0; ks < 2; ++ks)
        aQ[ks] = *(const short8*)(Q + base +
            (size_t)(qt * 16 + l16) * Hc + ks * 32 + quad * 8);

    floatx4 acc[4];
    float l_st[4];
    #pragma unroll
    for (int nh = 0; nh < 4; ++nh)
        #pragma unroll
        for (int r = 0; r < 4; ++r) acc[nh][r] = 0.f;
    #pragma unroll
    for (int r = 0; r < 4; ++r) l_st[r] = 0.f;

    for (int kb = wv * 64; kb < qend; kb += 512) {
        floatx4 s[4];
        #pragma unroll
        for (int ni = 0; ni < 4; ++ni)
            #pragma unroll
            for (int r = 0; r < 4; ++r) s[ni][r] = 0.f;
        #pragma unroll
        for (int ks = 0; ks < 2; ++ks) {
            short8 bk[4];
            #pragma unroll
            for (int ni = 0; ni < 4; ++ni)
                bk[ni] = *(const short8*)(K + base +
                    (size_t)(kb + 16 * ni + l16) * Hc + ks * 32 + quad * 8);
            __builtin_amdgcn_s_setprio(1);
            #pragma unroll
            for (int ni = 0; ni < 4; ++ni)
                s[ni] = __builtin_amdgcn_mfma_f32_16x16x32_bf16(aQ[ks], bk[ni], s[ni], 0, 0, 0);
            __builtin_amdgcn_s_setprio(0);
        }

        #pragma unroll
        for (int r = 0; r < 4; ++r) {
            const int qrow = qt * 16 + quad * 4 + r;
            #pragma unroll
            for (int ni = 0; ni < 4; ++ni) {
                const int kcol = kb + 16 * ni + l16;
                const float p = (kcol > qrow) ? 0.f : __expf(s[ni][r] * SCALE);
                s[ni][r] = p;
                l_st[r] += p;
            }
        }
        #pragma unroll
        for (int ni = 0; ni < 4; ++ni)
            #pragma unroll
            for (int r = 0; r < 4; ++r)
                Pb[wv][quad * 4 + r][16 * ni + l16] = f2bf(s[ni][r]);

        #pragma unroll
        for (int ks = 0; ks < 2; ++ks) {
            const short8 aP = *(const short8*)&Pb[wv][l16][ks * 32 + quad * 8];
            short8 bv[4];
            #pragma unroll
            for (int nh = 0; nh < 4; ++nh)
                bv[nh] = *(const short8*)(VtB +
                    (size_t)(16 * nh + l16) * Tc + kb + ks * 32 + quad * 8);
            __builtin_amdgcn_s_setprio(1);
            #pragma unroll
            for (int nh = 0; nh < 4; ++nh)
                acc[nh] = __builtin_amdgcn_mfma_f32_16x16x32_bf16(aP, bv[nh], acc[nh], 0, 0, 0);
            __builtin_amdgcn_s_setprio(0);
        }
    }

    #pragma unroll
    for (int nh = 0; nh < 4; ++nh)
        #pragma unroll
        for (int r = 0; r < 4; ++r)
            accS[wv][quad * 4 + r][16 * nh + l16] = acc[nh][r];
    // reduce l_st across the 16 lanes of each quad (xor masks 1,2,4,8 stay
    // within the 16-lane group), then one scalar per (wave, q-row)
    #pragma unroll
    for (int r = 0; r < 4; ++r) {
        float v = l_st[r];
        v += __shfl_xor(v, 1);
        v += __shfl_xor(v, 2);
        v += __shfl_xor(v, 4);
        v += __shfl_xor(v, 8);
        l_st[r] = v;
    }
    if (l16 == 0)
        #pragma unroll
        for (int r = 0; r < 4; ++r)
            lSr[wv][quad * 4 + r] = l_st[r];
    __syncthreads();

    {
        const int q  = tid >> 5;              // 0..15
        const int h0 = (tid & 31) * 2;        // 0..62
        float denom = 0.f;
        #pragma unroll
        for (int w = 0; w < 8; ++w)
            denom += lSr[w][q];
        const float inv = 1.f / denom;
        float o0 = 0.f, o1 = 0.f;
        #pragma unroll
        for (int w = 0; w < 8; ++w) {
            const float2 v = *(const float2*)&accS[w][q][h0];
            o0 += v.x; o1 += v.y;
        }
        o0 *= inv; o1 *= inv;
        if (!(o0 > -1.0e5f && o0 < 1.0e5f)) o0 = 555.0f;   // diag
        if (!(o1 > -1.0e5f && o1 < 1.0e5f)) o1 = 555.0f;
        float2 st; st.x = o0; st.y = o1;
        *(float2*)(Out + base + (size_t)(qt * 16 + q) * Hc + h0) = st;
    }
}

extern "C" void kernel_launch(void* const* d_in, const int* in_sizes, int n_in,
                              void* d_out, int out_size, void* d_ws, size_t ws_size,
                              hipStream_t stream)
{
    const float* X  = (const float*)d_in[0];
    const float* Wq = (const float*)d_in[1];
    const float* Wk = (const float*)d_in[2];
    const float* Wv = (const float*)d_in[3];

    const size_t N = (size_t)Bc * Tc * Hc;          // 524,288
    unsigned short* Wt  = (unsigned short*)d_ws;    // 384 KB bf16 W^T x3
    unsigned short* Qws = Wt + 3 * (size_t)Ec * Hc; // 1 MB
    unsigned short* Kws = Qws + N;                  // 1 MB
    unsigned short* Vtw = Kws + N;                  // 1 MB (V^T [b][h][t])

    prep_w<<<dim3(64, 3), dim3(256), 0, stream>>>(Wq, Wk, Wv, Wt);
    qkv_mfma9<<<dim3(256), dim3(512), 0, stream>>>(X, Wt, Qws, Kws, Vtw);
    attn_mfma6<<<dim3(128, 4), dim3(512), 0, stream>>>(
        Qws, Kws, Vtw, (float*)d_out);
}

// Round 3
// 107.030 us; speedup vs baseline: 1.2157x; 1.2157x over previous
//
#include <hip/hip_runtime.h>
#include <hip/hip_bf16.h>

// (B,T,E,H) = (4, 2048, 1024, 64); scale = E^-0.5 = 1/32.
// Ground truth: inputs fp32, output fp32 (r7-r12 pass). ws >= 268 MB.
// dur_us model: ~87 us fixed harness ops (ws poison fill = 44 us x2) + kernels.
// R15: REVERT qkv to proven qkv_mfma8 (R13/R14's 32-row 1-block/CU variant
// stalled: MfmaUtil 2.5%, VALUBusy 4%, HBM 18% -> phase overlap came from
// 2 blocks/CU TLP, not intra-block scheduling; do not remove it again).
// KEEP attn_mfma6 (balanced qt pairing + shfl-reduced lS + setprio) — ran
// clean in R14, absmax unchanged; this round isolates its delta.
constexpr int Bc = 4;
constexpr int Tc = 2048;
constexpr int Ec = 1024;
constexpr int Hc = 64;
constexpr float SCALE = 0.03125f;

typedef short  short8  __attribute__((ext_vector_type(8)));
typedef float  floatx4 __attribute__((ext_vector_type(4)));

__device__ __forceinline__ unsigned short f2bf(float f) {  // RNE
    union { float f; unsigned int i; } x;
    x.f = f;
    unsigned int r = x.i + 0x7fffu + ((x.i >> 16) & 1u);
    return (unsigned short)(r >> 16);
}

// ---------------------------------------------------------------------------
// Kernel 0: W fp32 [E][H] -> Wt bf16 [H][E], x3 (r7-r12-proven). ~3 us.
// ---------------------------------------------------------------------------
__global__ __launch_bounds__(256) void prep_w(
    const float* __restrict__ Wq, const float* __restrict__ Wk,
    const float* __restrict__ Wv, unsigned short* __restrict__ Wt)
{
    const float* W = blockIdx.y == 0 ? Wq : (blockIdx.y == 1 ? Wk : Wv);
    unsigned short* D = Wt + (size_t)blockIdx.y * (Ec * Hc);
    const int i0 = blockIdx.x * 1024 + threadIdx.x * 4;
    const float4 f = *(const float4*)(W + i0);
    const float v[4] = {f.x, f.y, f.z, f.w};
    #pragma unroll
    for (int j = 0; j < 4; ++j) {
        const int i = i0 + j;            // i = e*64 + h
        D[(i & 63) * Ec + (i >> 6)] = f2bf(v[j]);
    }
}

// ---------------------------------------------------------------------------
// Kernel 1: FUSED QKV projection, MFMA 16x16x32 bf16, K=128 staging depth.
// PROVEN (r12 baseline, 119.8 us total): grid 512 x 256 thr (exactly
// 2 blocks/CU -> 55 KB LDS is free; the 2-block co-residency IS the
// pipeline — one block's MFMA phase covers the other's staging drain).
// Block = 16 X-rows, all three matrices. Per K=128 stage: X fp32->bf16
// (2 float4/thr, coalesced) into Xs[16][136]; all 3 W^T tiles (12 uint4/thr,
// L2) into Ws[3][64][136]. Barriers: 16 total.
// Pad-136 rows: 2-way-free bank math (68%32==4, proven pad-72 class).
// Wave w owns output frags f=3w..3w+2 (which=f>>2, ni=f&3) — r9/r12-proven.
// ---------------------------------------------------------------------------
__global__ __launch_bounds__(256) void qkv_mfma8(
    const float* __restrict__ X, const unsigned short* __restrict__ Wt,
    unsigned short* __restrict__ Q, unsigned short* __restrict__ K,
    unsigned short* __restrict__ Vt)
{
    __shared__ __align__(16) unsigned short Xs[16][136];      //  4.25 KB
    __shared__ __align__(16) unsigned short Ws[3][64][136];   // 51.0 KB

    const int tid  = threadIdx.x;
    const int wv   = tid >> 6;
    const int lane = tid & 63;
    const int quad = lane >> 4;
    const int l16  = lane & 15;
    const size_t row0 = (size_t)blockIdx.x * 16;

    floatx4 acc[3];
    #pragma unroll
    for (int j = 0; j < 3; ++j)
        #pragma unroll
        for (int r = 0; r < 4; ++r) acc[j][r] = 0.f;

    const int xrow = tid >> 4;         // 0..15
    const int xc4  = (tid & 15) * 4;   // 0,4,..,60  (covers 64 cols per half)

    for (int k0 = 0; k0 < Ec; k0 += 128) {
        __syncthreads();
        // Stage X (fp32 -> bf16): 16 rows x 128 cols; 2 x 16 B/thread.
        #pragma unroll
        for (int h = 0; h < 2; ++h) {
            const float4 f = *(const float4*)(X + (row0 + xrow) * Ec + k0 + h * 64 + xc4);
            uint2 p;
            p.x = (unsigned int)f2bf(f.x) | ((unsigned int)f2bf(f.y) << 16);
            p.y = (unsigned int)f2bf(f.z) | ((unsigned int)f2bf(f.w) << 16);
            *(uint2*)&Xs[xrow][h * 64 + xc4] = p;
        }
        // Stage 3 W^T tiles: 3 x 64 x 128 bf16 = 48 KB; 12 x 16 B/thread,
        // back-to-back (deep MLP). flat = which*1024 + r*16 + c8chunk.
        #pragma unroll
        for (int j = 0; j < 12; ++j) {
            const int flat  = tid + 256 * j;        // 0..3071
            const int which = flat >> 10;           // 1024 chunks per matrix
            const int r     = (flat >> 4) & 63;     // h row
            const int c8    = (flat & 15) * 8;      // e col (8 elems, 0..120)
            *(uint4*)&Ws[which][r][c8] =
                *(const uint4*)(Wt + which * 65536 + r * 1024 + k0 + c8);
        }
        __syncthreads();

        #pragma unroll
        for (int ks = 0; ks < 4; ++ks) {
            const short8 a = *(const short8*)&Xs[l16][ks * 32 + quad * 8];
            short8 b[3];
            #pragma unroll
            for (int j = 0; j < 3; ++j) {
                const int f = 3 * wv + j;
                b[j] = *(const short8*)&Ws[f >> 2][16 * (f & 3) + l16][ks * 32 + quad * 8];
            }
            #pragma unroll
            for (int j = 0; j < 3; ++j)
                acc[j] = __builtin_amdgcn_mfma_f32_16x16x32_bf16(a, b[j], acc[j], 0, 0, 0);
        }
    }

    // Epilogue. C/D: col = lane&15, row = quad*4 + reg (r7-r12-proven).
    #pragma unroll
    for (int j = 0; j < 3; ++j) {
        const int f  = 3 * wv + j;
        const int mf = f >> 2, nf = f & 3;
        if (mf < 2) {
            unsigned short* O = mf == 0 ? Q : K;
            #pragma unroll
            for (int r = 0; r < 4; ++r) {
                float x = acc[j][r];
                if (!(x > -1.0e4f && x < 1.0e4f)) x = 11111.0f;   // diag
                O[(row0 + quad * 4 + r) * Hc + 16 * nf + l16] = f2bf(x);
            }
        } else {
            // V^T: Vt[b][h][t] (r8-proven). 16-row block shares one b.
            const size_t b  = row0 >> 11;
            const int    t0 = (int)(row0 & 2047) + quad * 4;
            unsigned short* VtB = Vt + b * ((size_t)Hc * Tc);
            unsigned int pk[2];
            #pragma unroll
            for (int half = 0; half < 2; ++half) {
                float x0 = acc[j][half * 2 + 0], x1 = acc[j][half * 2 + 1];
                if (!(x0 > -1.0e4f && x0 < 1.0e4f)) x0 = 11111.0f;
                if (!(x1 > -1.0e4f && x1 < 1.0e4f)) x1 = 11111.0f;
                pk[half] = (unsigned int)f2bf(x0) | ((unsigned int)f2bf(x1) << 16);
            }
            uint2 st; st.x = pk[0]; st.y = pk[1];
            *(uint2*)(VtB + (size_t)(16 * nf + l16) * Tc + t0) = st;
        }
    }
}

// ---------------------------------------------------------------------------
// Kernel 2: causal flash attention — r10/r11/r12-proven core, R13 polish
// (ran clean in R14, absmax unchanged):
//  * balanced dispatch: first 256 blocks qt=127..64 (desc), next 256 qt=0..63
//    (asc) -> CU c gets (heavy, light) pair summing to constant 129 k-tiles
//    (was: c and c+256 equally heavy -> up-to-2x-mean tail).
//  * lS pre-reduced across l16 via 4x shfl_xor -> epilogue denom 8 LDS reads
//    (was 128 scalar), lS LDS 8 KB -> 0.5 KB.
//  * accS epilogue reads as float2.
//  * s_setprio(1) around MFMA clusters (barrier-free independent waves in
//    main loop — the m191-positive regime).
// ---------------------------------------------------------------------------
__global__ __launch_bounds__(512, 4) void attn_mfma6(
    const unsigned short* __restrict__ Q, const unsigned short* __restrict__ K,
    const unsigned short* __restrict__ Vt, float* __restrict__ Out)
{
    __shared__ __align__(16) unsigned short Pb[8][16][72];   // 18 KB
    __shared__ __align__(16) float accS[8][16][64];          // 32 KB
    __shared__ __align__(16) float lSr[8][16];               // 0.5 KB

    const int tid  = threadIdx.x;
    const int wv   = tid >> 6;            // 0..7
    const int lane = tid & 63;
    const int quad = lane >> 4;
    const int l16  = lane & 15;
    // balanced heavy/light pairing over dispatch-linear id
    const int id   = blockIdx.x + 128 * blockIdx.y;   // 0..511, dispatch order
    const int jj   = id & 255;
    const int qt   = (id < 256) ? (127 - (jj >> 2)) : (jj >> 2);
    const int b    = jj & 3;
    const int qend = qt * 16 + 16;
    const size_t base = (size_t)b * Tc * Hc;
    const unsigned short* VtB = Vt + (size_t)b * Hc * Tc;

    short8 aQ[2];
    #pragma unroll
    for (int ks = 0; ks < 2; ++ks)
        aQ[ks] = *(const short8*)(Q + base +
            (size_t)(qt * 16 + l16) * Hc + ks * 32 + quad * 8);

    floatx4 acc[4];
    float l_st[4];
    #pragma unroll
    for (int nh = 0; nh < 4; ++nh)
        #pragma unroll
        for (int r = 0; r < 4; ++r) acc[nh][r] = 0.f;
    #pragma unroll
    for (int r = 0; r < 4; ++r) l_st[r] = 0.f;

    for (int kb = wv * 64; kb < qend; kb += 512) {
        floatx4 s[4];
        #pragma unroll
        for (int ni = 0; ni < 4; ++ni)
            #pragma unroll
            for (int r = 0; r < 4; ++r) s[ni][r] = 0.f;
        #pragma unroll
        for (int ks = 0; ks < 2; ++ks) {
            short8 bk[4];
            #pragma unroll
            for (int ni = 0; ni < 4; ++ni)
                bk[ni] = *(const short8*)(K + base +
                    (size_t)(kb + 16 * ni + l16) * Hc + ks * 32 + quad * 8);
            __builtin_amdgcn_s_setprio(1);
            #pragma unroll
            for (int ni = 0; ni < 4; ++ni)
                s[ni] = __builtin_amdgcn_mfma_f32_16x16x32_bf16(aQ[ks], bk[ni], s[ni], 0, 0, 0);
            __builtin_amdgcn_s_setprio(0);
        }

        #pragma unroll
        for (int r = 0; r < 4; ++r) {
            const int qrow = qt * 16 + quad * 4 + r;
            #pragma unroll
            for (int ni = 0; ni < 4; ++ni) {
                const int kcol = kb + 16 * ni + l16;
                const float p = (kcol > qrow) ? 0.f : __expf(s[ni][r] * SCALE);
                s[ni][r] = p;
                l_st[r] += p;
            }
        }
        #pragma unroll
        for (int ni = 0; ni < 4; ++ni)
            #pragma unroll
            for (int r = 0; r < 4; ++r)
                Pb[wv][quad * 4 + r][16 * ni + l16] = f2bf(s[ni][r]);

        #pragma unroll
        for (int ks = 0; ks < 2; ++ks) {
            const short8 aP = *(const short8*)&Pb[wv][l16][ks * 32 + quad * 8];
            short8 bv[4];
            #pragma unroll
            for (int nh = 0; nh < 4; ++nh)
                bv[nh] = *(const short8*)(VtB +
                    (size_t)(16 * nh + l16) * Tc + kb + ks * 32 + quad * 8);
            __builtin_amdgcn_s_setprio(1);
            #pragma unroll
            for (int nh = 0; nh < 4; ++nh)
                acc[nh] = __builtin_amdgcn_mfma_f32_16x16x32_bf16(aP, bv[nh], acc[nh], 0, 0, 0);
            __builtin_amdgcn_s_setprio(0);
        }
    }

    #pragma unroll
    for (int nh = 0; nh < 4; ++nh)
        #pragma unroll
        for (int r = 0; r < 4; ++r)
            accS[wv][quad * 4 + r][16 * nh + l16] = acc[nh][r];
    // reduce l_st across the 16 lanes of each quad (xor masks 1,2,4,8 stay
    // within the 16-lane group), then one scalar per (wave, q-row)
    #pragma unroll
    for (int r = 0; r < 4; ++r) {
        float v = l_st[r];
        v += __shfl_xor(v, 1);
        v += __shfl_xor(v, 2);
        v += __shfl_xor(v, 4);
        v += __shfl_xor(v, 8);
        l_st[r] = v;
    }
    if (l16 == 0)
        #pragma unroll
        for (int r = 0; r < 4; ++r)
            lSr[wv][quad * 4 + r] = l_st[r];
    __syncthreads();

    {
        const int q  = tid >> 5;              // 0..15
        const int h0 = (tid & 31) * 2;        // 0..62
        float denom = 0.f;
        #pragma unroll
        for (int w = 0; w < 8; ++w)
            denom += lSr[w][q];
        const float inv = 1.f / denom;
        float o0 = 0.f, o1 = 0.f;
        #pragma unroll
        for (int w = 0; w < 8; ++w) {
            const float2 v = *(const float2*)&accS[w][q][h0];
            o0 += v.x; o1 += v.y;
        }
        o0 *= inv; o1 *= inv;
        if (!(o0 > -1.0e5f && o0 < 1.0e5f)) o0 = 555.0f;   // diag
        if (!(o1 > -1.0e5f && o1 < 1.0e5f)) o1 = 555.0f;
        float2 st; st.x = o0; st.y = o1;
        *(float2*)(Out + base + (size_t)(qt * 16 + q) * Hc + h0) = st;
    }
}

extern "C" void kernel_launch(void* const* d_in, const int* in_sizes, int n_in,
                              void* d_out, int out_size, void* d_ws, size_t ws_size,
                              hipStream_t stream)
{
    const float* X  = (const float*)d_in[0];
    const float* Wq = (const float*)d_in[1];
    const float* Wk = (const float*)d_in[2];
    const float* Wv = (const float*)d_in[3];

    const size_t N = (size_t)Bc * Tc * Hc;          // 524,288
    unsigned short* Wt  = (unsigned short*)d_ws;    // 384 KB bf16 W^T x3
    unsigned short* Qws = Wt + 3 * (size_t)Ec * Hc; // 1 MB
    unsigned short* Kws = Qws + N;                  // 1 MB
    unsigned short* Vtw = Kws + N;                  // 1 MB (V^T [b][h][t])

    prep_w<<<dim3(64, 3), dim3(256), 0, stream>>>(Wq, Wk, Wv, Wt);
    qkv_mfma8<<<dim3(512), dim3(256), 0, stream>>>(X, Wt, Qws, Kws, Vtw);
    attn_mfma6<<<dim3(128, 4), dim3(512), 0, stream>>>(
        Qws, Kws, Vtw, (float*)d_out);
}